// Round 1
// baseline (232.268 us; speedup 1.0000x reference)
//
#include <hip/hip_runtime.h>

// GE2E loss: input [N=1024][M=20][D=256] fp32, scalars w, b -> scalar loss.
//
// Decomposition:
//   Kernel A (per speaker): centroid c, cc=||c||^2; write c_hat transposed
//     [D][N] for coalesced column access in kernel B. Per (n,m): uu=||u||^2,
//     uc=u.c -> alpha = w/||u||, s_self = w*cos(u,excl), s_own = w*cos(u,c).
//     (excl stats derived algebraically from uu, uc, cc.)  Also zeroes d_out.
//   Kernel B: row-panel GEMM raw_input[rows] x c_hatT -> sim row (scaled by
//     alpha in epilogue; b cancels), block-wide logsumexp per row, self-column
//     corrected via s_own/s_self, atomicAdd partial loss.

#define D_DIM 256
#define N_SPK 1024
#define M_UTT 20
#define RT    16   // rows per block in kernel B

__device__ __forceinline__ float block_sum(float v, float* red, int tid) {
#pragma unroll
  for (int o = 32; o; o >>= 1) v += __shfl_xor(v, o, 64);
  __syncthreads();
  if ((tid & 63) == 0) red[tid >> 6] = v;
  __syncthreads();
  return red[0] + red[1] + red[2] + red[3];
}

__device__ __forceinline__ float block_max(float v, float* red, int tid) {
#pragma unroll
  for (int o = 32; o; o >>= 1) v = fmaxf(v, __shfl_xor(v, o, 64));
  __syncthreads();
  if ((tid & 63) == 0) red[tid >> 6] = v;
  __syncthreads();
  return fmaxf(fmaxf(red[0], red[1]), fmaxf(red[2], red[3]));
}

// ---------------- Kernel A: per-speaker prep ----------------
__global__ __launch_bounds__(256) void ge2e_prep(
    const float* __restrict__ inp, const float* __restrict__ wp,
    float* __restrict__ c_hatT, float* __restrict__ alpha,
    float* __restrict__ sself, float* __restrict__ sown,
    float* __restrict__ out) {
  const int n = blockIdx.x;
  const int d = threadIdx.x;  // one thread per embedding dim
  if (n == 0 && d == 0) out[0] = 0.0f;  // kernel A completes before B (stream order)
  const float w = wp[0];

  __shared__ float red1[4];
  __shared__ float2 red2[4];

  const float* up = inp + (size_t)n * (M_UTT * D_DIM) + d;
  float u[M_UTT];
#pragma unroll
  for (int m = 0; m < M_UTT; ++m) u[m] = up[(size_t)m * D_DIM];

  float c = 0.0f;
#pragma unroll
  for (int m = 0; m < M_UTT; ++m) c += u[m];
  c *= (1.0f / (float)M_UTT);

  const float cc = block_sum(c * c, red1, d);
  // transposed write (scattered, one-time, ~1 MB logical)
  c_hatT[(size_t)d * N_SPK + n] = c * rsqrtf(cc);

  for (int m = 0; m < M_UTT; ++m) {
    float a = u[m] * u[m];   // -> uu
    float bv = u[m] * c;     // -> uc
#pragma unroll
    for (int o = 32; o; o >>= 1) {
      a += __shfl_xor(a, o, 64);
      bv += __shfl_xor(bv, o, 64);
    }
    __syncthreads();
    if ((d & 63) == 0) red2[d >> 6] = make_float2(a, bv);
    __syncthreads();
    if (d == 0) {
      const float uu = red2[0].x + red2[1].x + red2[2].x + red2[3].x;
      const float uc = red2[0].y + red2[1].y + red2[2].y + red2[3].y;
      const float Mf = (float)M_UTT;
      const float ue = (Mf * uc - uu) * (1.0f / (Mf - 1.0f));
      const float ee = (Mf * Mf * cc - 2.0f * Mf * uc + uu) *
                       (1.0f / ((Mf - 1.0f) * (Mf - 1.0f)));
      const int r = n * M_UTT + m;
      sself[r] = w * ue * rsqrtf(uu * ee);  // w * cos(u, excl)
      sown[r]  = w * uc * rsqrtf(uu * cc);  // w * cos(u, c)  (the overridden col)
      alpha[r] = w * rsqrtf(uu);
    }
  }
}

// ---------------- Kernel B: GEMM + fused logsumexp ----------------
__global__ __launch_bounds__(256) void ge2e_main(
    const float* __restrict__ inp, const float* __restrict__ c_hatT,
    const float* __restrict__ alpha, const float* __restrict__ sself,
    const float* __restrict__ sown, float* __restrict__ out) {
  __shared__ __align__(16) float uT[D_DIM * RT];  // [d][r], 16 KB
  __shared__ float rcA[RT], rcS[RT], rcO[RT];
  __shared__ float red[4];
  const int tid = threadIdx.x;
  const int r0 = blockIdx.x * RT;

  // stage 16 rows of raw input, transposed to [d][r] for b128 broadcast reads
  const float* src = inp + (size_t)r0 * D_DIM;
#pragma unroll
  for (int j = 0; j < RT; ++j)
    uT[(size_t)tid * RT + j] = src[(size_t)j * D_DIM + tid];
  if (tid < RT) {
    rcA[tid] = alpha[r0 + tid];
    rcS[tid] = sself[r0 + tid];
    rcO[tid] = sown[r0 + tid];
  }
  __syncthreads();

  float4 acc[RT];
#pragma unroll
  for (int r = 0; r < RT; ++r) acc[r] = make_float4(0.f, 0.f, 0.f, 0.f);

  // thread owns columns 4*tid .. 4*tid+3 (coalesced float4 from c_hatT[d][..])
  const float* cp = c_hatT + 4 * tid;
#pragma unroll 4
  for (int d = 0; d < D_DIM; ++d) {
    const float4 cv = *reinterpret_cast<const float4*>(cp + (size_t)d * N_SPK);
    const float4* uv = reinterpret_cast<const float4*>(uT + d * RT);
    const float4 u0 = uv[0], u1 = uv[1], u2 = uv[2], u3 = uv[3];
    const float us[RT] = {u0.x, u0.y, u0.z, u0.w, u1.x, u1.y, u1.z, u1.w,
                          u2.x, u2.y, u2.z, u2.w, u3.x, u3.y, u3.z, u3.w};
#pragma unroll
    for (int r = 0; r < RT; ++r) {
      acc[r].x = fmaf(us[r], cv.x, acc[r].x);
      acc[r].y = fmaf(us[r], cv.y, acc[r].y);
      acc[r].z = fmaf(us[r], cv.z, acc[r].z);
      acc[r].w = fmaf(us[r], cv.w, acc[r].w);
    }
  }

  float loss = 0.0f;
  for (int r = 0; r < RT; ++r) {
    const float a = rcA[r];
    const float s0 = a * acc[r].x, s1 = a * acc[r].y;
    const float s2 = a * acc[r].z, s3 = a * acc[r].w;
    const float mx = block_max(fmaxf(fmaxf(s0, s1), fmaxf(s2, s3)), red, tid);
    const float e = __expf(s0 - mx) + __expf(s1 - mx) +
                    __expf(s2 - mx) + __expf(s3 - mx);
    float se = block_sum(e, red, tid);
    if (tid == 0) {
      const float ss = rcS[r], so = rcO[r];
      se += __expf(ss - mx) - __expf(so - mx);  // swap own col -> excl col
      loss += mx + __logf(se) - ss;             // LSE - sim_self (b cancels)
    }
  }
  if (tid == 0) atomicAdd(out, loss);
}

extern "C" void kernel_launch(void* const* d_in, const int* in_sizes, int n_in,
                              void* d_out, int out_size, void* d_ws, size_t ws_size,
                              hipStream_t stream) {
  const float* inp = (const float*)d_in[0];
  const float* wp  = (const float*)d_in[1];
  // d_in[2] (b) is provably unused: it cancels in LSE - sim_self.
  float* out = (float*)d_out;

  float* c_hatT = (float*)d_ws;                    // [D][N]  = 256*1024 floats
  float* alpha  = c_hatT + D_DIM * N_SPK;          // [N*M]
  float* sself  = alpha + N_SPK * M_UTT;           // [N*M]
  float* sown   = sself + N_SPK * M_UTT;           // [N*M]

  ge2e_prep<<<N_SPK, 256, 0, stream>>>(inp, wp, c_hatT, alpha, sself, sown, out);
  ge2e_main<<<(N_SPK * M_UTT) / RT, 256, 0, stream>>>(inp, c_hatT, alpha, sself,
                                                      sown, out);
}

// Round 2
// 98.175 us; speedup vs baseline: 2.3658x; 2.3658x over previous
//
#include <hip/hip_runtime.h>

// GE2E loss, bf16-MFMA version.
//   Kernel A (1024 blocks): centroid c (fp32, [N][D]), cc=||c||^2 ([N]),
//     c_hat in bf16 pre-swizzled into 32x32x16 MFMA B-fragment order. Zeroes out.
//   Kernel B (640 blocks, 4 waves): 32 rows x 1024 cols. Stage raw u rows ->
//     bf16 LDS in A-frag order + per-row uu=||u||^2, uc=u.c (fp32 exact).
//     Each wave: 8 col-tiles of 32; per tile 16 MFMAs (2 indep 8-chains) then
//     exp-accumulate (no max-sub: |sim|<=w=10, fp32-safe). Self-col correction
//     from uu/uc/cc scalars. One atomicAdd per block.

#define D_DIM 256
#define N_SPK 1024
#define M_UTT 20

typedef __bf16 bf16x8 __attribute__((ext_vector_type(8)));
typedef float f32x16 __attribute__((ext_vector_type(16)));

__device__ __forceinline__ float block_sum256(float v, float* red, int tid) {
#pragma unroll
  for (int o = 32; o; o >>= 1) v += __shfl_xor(v, o, 64);
  __syncthreads();
  if ((tid & 63) == 0) red[tid >> 6] = v;
  __syncthreads();
  return red[0] + red[1] + red[2] + red[3];
}

// ---------------- Kernel A: centroid prep ----------------
__global__ __launch_bounds__(256) void ge2e_prep(
    const float* __restrict__ inp, __bf16* __restrict__ bsw,
    float* __restrict__ c_raw, float* __restrict__ ccv,
    float* __restrict__ out) {
  const int n = blockIdx.x, d = threadIdx.x;
  if (n == 0 && d == 0) out[0] = 0.0f;
  __shared__ float red[4];

  const float* up = inp + (size_t)n * (M_UTT * D_DIM) + d;
  float s = 0.0f;
#pragma unroll
  for (int m = 0; m < M_UTT; ++m) s += up[(size_t)m * D_DIM];
  const float c = s * (1.0f / (float)M_UTT);
  c_raw[(size_t)n * D_DIM + d] = c;

  const float cc = block_sum256(c * c, red, d);
  if (d == 0) ccv[n] = cc;

  // B-frag swizzle for 32x32x16: lane holds B[n=lane&31][k=(lane>>5)*8+j].
  // layout: [tile(n>>5)][kstep(k>>4)][half((k>>3)&1)*32 + (n&31)][j(k&7)]
  const int tile = n >> 5, n5 = n & 31, ks = d >> 4, half = (d >> 3) & 1,
            j = d & 7;
  bsw[(size_t)(((tile * 16 + ks) * 64 + half * 32 + n5) * 8 + j)] =
      (__bf16)(c * rsqrtf(cc));
}

// ---------------- Kernel B: MFMA GEMM + fused sumexp ----------------
__global__ __launch_bounds__(256, 2) void ge2e_main(
    const float* __restrict__ inp, const float* __restrict__ wp,
    const __bf16* __restrict__ bsw, const float* __restrict__ c_raw,
    const float* __restrict__ ccv, float* __restrict__ out) {
  __shared__ __align__(16) __bf16 lA[32 * D_DIM];  // 16 KB, A-frag order
  __shared__ float uuL[32], ucL[32], ccL[32], a2L[32];
  __shared__ float rowtot[4][32];
  const int tid = threadIdx.x;
  const int r0 = blockIdx.x * 32;
  const float w = wp[0];

  // ---- staging: 8 threads per row, 32 elems each ----
  {
    const int m = tid >> 3, seg = tid & 7;
    const int r = r0 + m, nr = r / M_UTT;
    const float* urow = inp + (size_t)r * D_DIM + seg * 32;
    const float* crow = c_raw + (size_t)nr * D_DIM + seg * 32;
    float uu = 0.f, uc = 0.f;
    bf16x8* lAv = reinterpret_cast<bf16x8*>(lA);
#pragma unroll
    for (int t = 0; t < 4; ++t) {
      const float4 f0 = reinterpret_cast<const float4*>(urow)[2 * t];
      const float4 f1 = reinterpret_cast<const float4*>(urow)[2 * t + 1];
      const float4 c0 = reinterpret_cast<const float4*>(crow)[2 * t];
      const float4 c1 = reinterpret_cast<const float4*>(crow)[2 * t + 1];
      uu += f0.x * f0.x + f0.y * f0.y + f0.z * f0.z + f0.w * f0.w +
            f1.x * f1.x + f1.y * f1.y + f1.z * f1.z + f1.w * f1.w;
      uc += f0.x * c0.x + f0.y * c0.y + f0.z * c0.z + f0.w * c0.w +
            f1.x * c1.x + f1.y * c1.y + f1.z * c1.z + f1.w * c1.w;
      bf16x8 pk;
      pk[0] = (__bf16)f0.x; pk[1] = (__bf16)f0.y;
      pk[2] = (__bf16)f0.z; pk[3] = (__bf16)f0.w;
      pk[4] = (__bf16)f1.x; pk[5] = (__bf16)f1.y;
      pk[6] = (__bf16)f1.z; pk[7] = (__bf16)f1.w;
      const int k = seg * 32 + t * 8;  // A-frag: [kstep][half*32+m][j]
      lAv[(k >> 4) * 64 + ((k >> 3) & 1) * 32 + m] = pk;
    }
#pragma unroll
    for (int o = 1; o < 8; o <<= 1) {
      uu += __shfl_xor(uu, o, 64);
      uc += __shfl_xor(uc, o, 64);
    }
    if (seg == 0) {
      uuL[m] = uu;
      ucL[m] = uc;
      ccL[m] = ccv[nr];
      a2L[m] = w * rsqrtf(uu);  // sim = a2 * (u . c_hat)
    }
  }
  __syncthreads();

  // ---- per-wave GEMM over 8 col-tiles of 32 ----
  const int lane = tid & 63, wv = tid >> 6, hl = lane >> 5;
  const bf16x8* lAv = reinterpret_cast<const bf16x8*>(lA);
  bf16x8 A[16];
#pragma unroll
  for (int ks = 0; ks < 16; ++ks) A[ks] = lAv[ks * 64 + lane];

  float a2v[16];
#pragma unroll
  for (int i = 0; i < 16; ++i)
    a2v[i] = a2L[(i & 3) + 8 * (i >> 2) + 4 * hl];

  float sume[16];
#pragma unroll
  for (int i = 0; i < 16; ++i) sume[i] = 0.0f;

  const bf16x8* Bv = reinterpret_cast<const bf16x8*>(bsw);
  for (int t = 0; t < 8; ++t) {
    const int tg = wv * 8 + t;
    const bf16x8* Bt = Bv + (size_t)tg * 1024 + lane;
    f32x16 acc0, acc1;
#pragma unroll
    for (int i = 0; i < 16; ++i) { acc0[i] = 0.0f; acc1[i] = 0.0f; }
#pragma unroll
    for (int ks = 0; ks < 8; ++ks) {
      acc0 = __builtin_amdgcn_mfma_f32_32x32x16_bf16(A[2 * ks], Bt[(2 * ks) * 64],
                                                     acc0, 0, 0, 0);
      acc1 = __builtin_amdgcn_mfma_f32_32x32x16_bf16(A[2 * ks + 1],
                                                     Bt[(2 * ks + 1) * 64],
                                                     acc1, 0, 0, 0);
    }
#pragma unroll
    for (int i = 0; i < 16; ++i)
      sume[i] += __expf(a2v[i] * (acc0[i] + acc1[i]));
  }

  // ---- reduce sumexp over the wave's 256 cols ----
#pragma unroll
  for (int i = 0; i < 16; ++i) {
    float v = sume[i];
#pragma unroll
    for (int o = 1; o < 32; o <<= 1) v += __shfl_xor(v, o, 64);
    sume[i] = v;
  }
  if ((lane & 31) == 0) {
#pragma unroll
    for (int i = 0; i < 16; ++i)
      rowtot[wv][(i & 3) + 8 * (i >> 2) + 4 * hl] = sume[i];
  }
  __syncthreads();

  // ---- per-row epilogue: self-column swap + log, block loss ----
  if (tid < 32) {
    const float se0 = rowtot[0][tid] + rowtot[1][tid] + rowtot[2][tid] +
                      rowtot[3][tid];
    const float uu = uuL[tid], uc = ucL[tid], cc = ccL[tid];
    const float Mf = (float)M_UTT;
    const float ue = (Mf * uc - uu) * (1.0f / (Mf - 1.0f));
    const float ee = (Mf * Mf * cc - 2.0f * Mf * uc + uu) *
                     (1.0f / ((Mf - 1.0f) * (Mf - 1.0f)));
    const float sself = w * ue * rsqrtf(uu * ee);
    const float sown = w * uc * rsqrtf(uu * cc);
    const float se = se0 + __expf(sself) - __expf(sown);
    float v = __logf(se) - sself;  // LSE - target logit (b cancels)
#pragma unroll
    for (int o = 1; o < 32; o <<= 1) v += __shfl_xor(v, o, 64);
    if (tid == 0) atomicAdd(out, v);
  }
}

extern "C" void kernel_launch(void* const* d_in, const int* in_sizes, int n_in,
                              void* d_out, int out_size, void* d_ws, size_t ws_size,
                              hipStream_t stream) {
  const float* inp = (const float*)d_in[0];
  const float* wp  = (const float*)d_in[1];
  // d_in[2] (b) cancels in LSE - sim_self.
  float* out = (float*)d_out;

  __bf16* bsw  = (__bf16*)d_ws;                       // 512 KB (frag-swizzled)
  float* c_raw = (float*)((char*)d_ws + 512 * 1024);  // 1 MB
  float* ccv   = c_raw + (size_t)N_SPK * D_DIM;       // 4 KB

  ge2e_prep<<<N_SPK, 256, 0, stream>>>(inp, bsw, c_raw, ccv, out);
  ge2e_main<<<(N_SPK * M_UTT) / 32, 256, 0, stream>>>(inp, wp, bsw, c_raw, ccv,
                                                      out);
}

// Round 4
// 92.340 us; speedup vs baseline: 2.5154x; 1.0632x over previous
//
#include <hip/hip_runtime.h>
#include <hip/hip_fp8.h>

// GE2E loss, fp8-MFMA v2 (armored). input [N=1024][M=20][D=256] fp32 -> scalar.
//   prep (256 blocks, 4 speakers/block, 1 wave each): centroid c (fp32 c_raw),
//     cc=||c||^2, c_hat -> fp8 e4m3 pre-swizzled into 32x32x16 fp8 MFMA B-frag
//     order (each lane stores 4 contiguous bytes = one u32). Zeroes out.
//   main (640 blocks, 4 waves, launch_bounds(256,2) -- natural VGPR ~150 gives
//     3 blocks/CU): 32 rows x 1024 cols. Staging: float4 loads, exact fp32
//     uu=||u||^2, uc=u.c; s=w*rsqrt(uu) folded into A before fp8 quantization
//     -> MFMA output IS the scaled similarity (b cancels). Per wave: 8
//     col-tiles of 32, software-pipelined B prefetch (load t+1 during t's
//     MFMAs); 16 MFMAs/tile (2 indep 8-chains); exp clamped (armor: NaN
//     structurally impossible -- corruption would surface as absmax, not NaN).
//     Self-col swap from exact fp32 scalars. One atomicAdd per block.

#define D_DIM 256
#define N_SPK 1024
#define M_UTT 20

typedef long lx2 __attribute__((ext_vector_type(2)));
typedef float f32x16 __attribute__((ext_vector_type(16)));

__device__ __forceinline__ int pk4_fp8(float x0, float x1, float x2, float x3) {
#if __has_builtin(__builtin_amdgcn_cvt_pk_fp8_f32)
  int v = __builtin_amdgcn_cvt_pk_fp8_f32(x0, x1, 0, false);
  v = __builtin_amdgcn_cvt_pk_fp8_f32(x2, x3, v, true);
  return v;
#else
  union { int i; unsigned char b[4]; } u;
  u.b[0] = __hip_fp8_e4m3(x0).__x;
  u.b[1] = __hip_fp8_e4m3(x1).__x;
  u.b[2] = __hip_fp8_e4m3(x2).__x;
  u.b[3] = __hip_fp8_e4m3(x3).__x;
  return u.i;
#endif
}

// ---------------- Kernel A: centroid prep (1 wave per speaker) ----------------
__global__ __launch_bounds__(256) void ge2e_prep(
    const float* __restrict__ inp, unsigned int* __restrict__ bsw32,
    float* __restrict__ c_raw, float* __restrict__ ccv,
    float* __restrict__ out) {
  const int tid = threadIdx.x, lane = tid & 63, wv = tid >> 6;
  const int s = blockIdx.x * 4 + wv;  // speaker; lane owns dims 4*lane..4*lane+3
  if (blockIdx.x == 0 && tid == 0) out[0] = 0.0f;

  const float4* up =
      reinterpret_cast<const float4*>(inp + (size_t)s * (M_UTT * D_DIM)) + lane;
  float4 a = make_float4(0.f, 0.f, 0.f, 0.f);
#pragma unroll
  for (int m = 0; m < M_UTT; ++m) {
    const float4 f = up[m * (D_DIM / 4)];
    a.x += f.x; a.y += f.y; a.z += f.z; a.w += f.w;
  }
  const float inv = 1.0f / (float)M_UTT;
  const float4 c = make_float4(a.x * inv, a.y * inv, a.z * inv, a.w * inv);
  reinterpret_cast<float4*>(c_raw + (size_t)s * D_DIM)[lane] = c;

  float cc = c.x * c.x + c.y * c.y + c.z * c.z + c.w * c.w;
#pragma unroll
  for (int o = 1; o < 64; o <<= 1) cc += __shfl_xor(cc, o, 64);
  if (lane == 0) ccv[s] = cc;

  const float r = rsqrtf(fmaxf(cc, 1e-20f));
  const int q = pk4_fp8(c.x * r, c.y * r, c.z * r, c.w * r);
  // B-frag: lane l holds B[n=l&31][k=(l>>5)*8+j]; mem [tile*8+kspair][64][16B].
  // d = 4*lane: ks=lane>>2, p=ks>>1, sub=ks&1, half=(lane>>1)&1, j0=(lane&1)*4.
  const int t = s >> 5, n5 = s & 31;
  const int p = lane >> 3, sub = (lane >> 2) & 1;
  const int half = (lane >> 1) & 1, jb = (lane & 1) * 4;
  bsw32[((((t * 8 + p) * 64) + half * 32 + n5) * 16 + sub * 8 + jb) >> 2] =
      (unsigned int)q;
}

// ---------------- Kernel B: fp8 MFMA GEMM + fused sumexp ----------------
__global__ __launch_bounds__(256, 2) void ge2e_main(
    const float* __restrict__ inp, const float* __restrict__ wp,
    const unsigned char* __restrict__ bsw, const float* __restrict__ c_raw,
    const float* __restrict__ ccv, float* __restrict__ out) {
  __shared__ __align__(16) unsigned char lA[32 * D_DIM];  // 8 KB, A-frag order
  __shared__ float uuL[32], ucL[32], ccL[32];
  __shared__ float rowtot[4][32];
  const int tid = threadIdx.x;
  const int r0 = blockIdx.x * 32;
  const float w = wp[0];

  // ---- staging: 8 threads per row; fold s=w/||u|| into fp8 A-frags ----
  {
    const int m = tid >> 3, seg = tid & 7;
    const int r = r0 + m, nr = r / M_UTT;
    const float4* urow =
        reinterpret_cast<const float4*>(inp + (size_t)r * D_DIM + seg * 32);
    const float4* crow =
        reinterpret_cast<const float4*>(c_raw + (size_t)nr * D_DIM + seg * 32);
    float4 uf[8];
    float uu = 0.f, uc = 0.f;
#pragma unroll
    for (int q = 0; q < 8; ++q) {
      uf[q] = urow[q];
      const float4 cf = crow[q];
      uu += uf[q].x * uf[q].x + uf[q].y * uf[q].y + uf[q].z * uf[q].z +
            uf[q].w * uf[q].w;
      uc += uf[q].x * cf.x + uf[q].y * cf.y + uf[q].z * cf.z + uf[q].w * cf.w;
    }
#pragma unroll
    for (int o = 1; o < 8; o <<= 1) {
      uu += __shfl_xor(uu, o, 64);
      uc += __shfl_xor(uc, o, 64);
    }
    const float s = w * rsqrtf(fmaxf(uu, 1e-20f));
    // A-frag: lane l holds A[m=l&31][k=(l>>5)*8+j]; mem [kspair][lane][sub*8+j]
    int4 ch0, ch1;
    ch0.x = pk4_fp8(s * uf[0].x, s * uf[0].y, s * uf[0].z, s * uf[0].w); // k0-3
    ch0.y = pk4_fp8(s * uf[1].x, s * uf[1].y, s * uf[1].z, s * uf[1].w); // k4-7
    ch0.z = pk4_fp8(s * uf[4].x, s * uf[4].y, s * uf[4].z, s * uf[4].w); // k16-19
    ch0.w = pk4_fp8(s * uf[5].x, s * uf[5].y, s * uf[5].z, s * uf[5].w); // k20-23
    ch1.x = pk4_fp8(s * uf[2].x, s * uf[2].y, s * uf[2].z, s * uf[2].w); // k8-11
    ch1.y = pk4_fp8(s * uf[3].x, s * uf[3].y, s * uf[3].z, s * uf[3].w); // k12-15
    ch1.z = pk4_fp8(s * uf[6].x, s * uf[6].y, s * uf[6].z, s * uf[6].w); // k24-27
    ch1.w = pk4_fp8(s * uf[7].x, s * uf[7].y, s * uf[7].z, s * uf[7].w); // k28-31
    reinterpret_cast<int4*>(lA)[seg * 64 + m] = ch0;       // half 0 (lanes <32)
    reinterpret_cast<int4*>(lA)[seg * 64 + m + 32] = ch1;  // half 1 (lanes >=32)
    if (seg == 0) {
      uuL[m] = uu;
      ucL[m] = uc;
      ccL[m] = ccv[nr];
    }
  }
  __syncthreads();

  const int lane = tid & 63, wv = tid >> 6, hl = lane >> 5;
  lx2 A[8];
  const lx2* lAv = reinterpret_cast<const lx2*>(lA);
#pragma unroll
  for (int p = 0; p < 8; ++p) A[p] = lAv[p * 64 + lane];

  float sume[16];
#pragma unroll
  for (int i = 0; i < 16; ++i) sume[i] = 0.0f;

  // ---- software-pipelined t-loop: prefetch B[t+1] during B[t]'s MFMAs ----
  const lx2* Bbase =
      reinterpret_cast<const lx2*>(bsw) + (size_t)(wv * 8) * 512 + lane;
  lx2 Bc[8];
#pragma unroll
  for (int p = 0; p < 8; ++p) Bc[p] = Bbase[p * 64];
#pragma unroll
  for (int t = 0; t < 8; ++t) {
    lx2 Bn[8];
    if (t < 7) {
      const lx2* Bt = Bbase + (t + 1) * 512;
#pragma unroll
      for (int p = 0; p < 8; ++p) Bn[p] = Bt[p * 64];
    }
    f32x16 acc0, acc1;
#pragma unroll
    for (int i = 0; i < 16; ++i) { acc0[i] = 0.0f; acc1[i] = 0.0f; }
#pragma unroll
    for (int p = 0; p < 8; ++p) {
      acc0 = __builtin_amdgcn_mfma_f32_32x32x16_fp8_fp8(A[p].x, Bc[p].x, acc0,
                                                        0, 0, 0);
      acc1 = __builtin_amdgcn_mfma_f32_32x32x16_fp8_fp8(A[p].y, Bc[p].y, acc1,
                                                        0, 0, 0);
    }
#pragma unroll
    for (int i = 0; i < 16; ++i)
      sume[i] += __expf(fminf(acc0[i] + acc1[i], 40.0f));  // armor: no inf
    if (t < 7) {
#pragma unroll
      for (int p = 0; p < 8; ++p) Bc[p] = Bn[p];
    }
  }

  // ---- reduce sumexp over the wave's 256 cols ----
#pragma unroll
  for (int i = 0; i < 16; ++i) {
    float v = sume[i];
#pragma unroll
    for (int o = 1; o < 32; o <<= 1) v += __shfl_xor(v, o, 64);
    sume[i] = v;
  }
  if ((lane & 31) == 0) {
#pragma unroll
    for (int i = 0; i < 16; ++i)
      rowtot[wv][(i & 3) + 8 * (i >> 2) + 4 * hl] = sume[i];
  }
  __syncthreads();

  // ---- per-row epilogue: self-column swap (exact fp32) + log ----
  if (tid < 32) {
    const float se0 = rowtot[0][tid] + rowtot[1][tid] + rowtot[2][tid] +
                      rowtot[3][tid];
    const float uu = uuL[tid], uc = ucL[tid], cc = ccL[tid];
    const float Mf = (float)M_UTT;
    const float ue = (Mf * uc - uu) * (1.0f / (Mf - 1.0f));
    const float ee = (Mf * Mf * cc - 2.0f * Mf * uc + uu) *
                     (1.0f / ((Mf - 1.0f) * (Mf - 1.0f)));
    const float sself = w * ue * rsqrtf(fmaxf(uu * ee, 1e-20f));
    const float sown = w * uc * rsqrtf(fmaxf(uu * cc, 1e-20f));
    const float se = fmaxf(
        se0 + __expf(fminf(sself, 40.f)) - __expf(fminf(sown, 40.f)), 1e-10f);
    float v = __logf(se) - sself;  // LSE - target logit (b cancels)
#pragma unroll
    for (int o = 1; o < 32; o <<= 1) v += __shfl_xor(v, o, 64);
    if (tid == 0) atomicAdd(out, v);
  }
}

extern "C" void kernel_launch(void* const* d_in, const int* in_sizes, int n_in,
                              void* d_out, int out_size, void* d_ws, size_t ws_size,
                              hipStream_t stream) {
  const float* inp = (const float*)d_in[0];
  const float* wp  = (const float*)d_in[1];
  // d_in[2] (b) cancels in LSE - sim_self.
  float* out = (float*)d_out;

  unsigned char* bsw = (unsigned char*)d_ws;            // 256 KB fp8 B-frags
  float* c_raw = (float*)((char*)d_ws + 256 * 1024);    // 1 MB
  float* ccv   = c_raw + (size_t)N_SPK * D_DIM;         // 4 KB

  ge2e_prep<<<N_SPK / 4, 256, 0, stream>>>(inp, (unsigned int*)bsw, c_raw, ccv,
                                           out);
  ge2e_main<<<(N_SPK * M_UTT) / 32, 256, 0, stream>>>(inp, wp, bsw, c_raw, ccv,
                                                      out);
}